// Round 8
// baseline (531.056 us; speedup 1.0000x reference)
//
#include <hip/hip_runtime.h>
#include <hip/hip_bf16.h>
#include <math.h>

#define NB 512
#define NT 256
#define NC 384
#define NH 64

typedef __bf16 bf16x8 __attribute__((ext_vector_type(8)));
typedef unsigned short u16x8 __attribute__((ext_vector_type(8)));
typedef unsigned short u16x4 __attribute__((ext_vector_type(4)));
typedef unsigned int   u32x2 __attribute__((ext_vector_type(2)));
typedef unsigned int   u32x4 __attribute__((ext_vector_type(4)));
typedef float f32x4 __attribute__((ext_vector_type(4)));

__device__ __forceinline__ unsigned short f2bf(float f) {
    union { float f; unsigned u; } v; v.f = f;
    unsigned r = v.u + 0x7FFFu + ((v.u >> 16) & 1u);   // round-to-nearest-even
    return (unsigned short)(r >> 16);
}

__device__ __forceinline__ unsigned pack2(float a, float b) {
    return (unsigned)f2bf(a) | ((unsigned)f2bf(b) << 16);
}

__device__ __forceinline__ f32x4 mfma16(bf16x8 a, bf16x8 b, f32x4 c) {
    return __builtin_amdgcn_mfma_f32_16x16x32_bf16(a, b, c, 0, 0, 0);
}

// ============ kernel 1: W -> Wf (bf16, MFMA fragment packed) ===================
// Wf element e = ((n*12+kk)*64 + l)*8 + j  holds  W_m[c=kk*32+8*(l>>4)+j][h=(n&3)*16+(l&15)]
// Same lane map serves as A-frag (row=l&15, k=8g+j) and B-frag. (verified r4-r7)
__global__ void prep_w(const float* __restrict__ Wq, const float* __restrict__ Wk,
                       const float* __restrict__ Wv, unsigned short* __restrict__ Wf) {
    const int e = blockIdx.x * 256 + threadIdx.x;   // 0..73727
    const int j  = e & 7;
    const int l  = (e >> 3) & 63;
    const int fi = e >> 9;                          // 0..143
    const int kk = fi % 12;
    const int n  = fi / 12;
    const int g = l >> 4, col = l & 15;
    const int c = kk * 32 + g * 8 + j;
    const int h = (n & 3) * 16 + col;
    const float* W = (n < 4) ? Wq : (n < 8 ? Wk : Wv);
    Wf[e] = f2bf(W[c * 64 + h]);
}

// ============ kernel 2: fused head, 8 waves, 2 blocks/CU =======================
// Wave w owns q-tiles {w, 15-w} (balanced causal). LDS (shorts):
//   K  [256][72]  @ 0       (immediate writes during chunk loop)
//   VT [64][264]  @ 18432   (deferred writes; region doubles as XS during staging)
//   XS [32][392]  @ 18432   (overlay; 32-row x chunks)
// Q never touches LDS: computed transposed (QT) and redistributed via shuffles.
#define HOFF_K   0
#define HLDK     72
#define HOFF_VT  18432
#define HLDVT    264
#define HOFF_XS  18432
#define HLDXS    392
#define HSMEM    35328          // 70,656 B -> 2 blocks/CU

__global__ __launch_bounds__(512, 4) void head_v5(
    const float* __restrict__ x, const unsigned short* __restrict__ Wf,
    float* __restrict__ out)
{
    __shared__ __align__(16) unsigned short SM[HSMEM];

    const int b    = blockIdx.x;
    const int tid  = threadIdx.x;
    const int w    = tid >> 6;       // wave 0..7
    const int lane = tid & 63;
    const int g    = lane >> 4;
    const int col  = lane & 15;

    unsigned Qlo[2][4], Qhi[2][4];   // QT D-frags, bf16-packed (per tile)
    unsigned Vlo[2][4], Vhi[2][4];   // V  D-frags, bf16-packed (per tile)

    // ---------------- phase 1+2: chunked staging + projection ----------------
    #pragma unroll 1
    for (int ch = 0; ch < 8; ++ch) {
        // stage 32 rows of x (coalesced float4 stream -> bf16 LDS)
        const float* xb = x + ((size_t)b * NT + ch * 32) * NC;
        #pragma unroll
        for (int k = 0; k < 3; ++k) {
            const int idx = k * 4096 + tid * 8;     // 512 thr x 8 f32
            const int row = idx / 384;              // 0..31
            const int cc  = idx - row * 384;
            const float4 f0 = *reinterpret_cast<const float4*>(xb + idx);
            const float4 f1 = *reinterpret_cast<const float4*>(xb + idx + 4);
            u16x8 u;
            u[0] = f2bf(f0.x); u[1] = f2bf(f0.y); u[2] = f2bf(f0.z); u[3] = f2bf(f0.w);
            u[4] = f2bf(f1.x); u[5] = f2bf(f1.y); u[6] = f2bf(f1.z); u[7] = f2bf(f1.w);
            *reinterpret_cast<u16x8*>(&SM[HOFF_XS + row * HLDXS + cc]) = u;
        }
        __syncthreads();

        #pragma unroll
        for (int mt = 0; mt < 2; ++mt) {
            const int MT = mt ? (15 - w) : w;
            if ((MT >> 1) == ch) {                  // wave-uniform ownership
                const int lr = (MT & 1) * 16 + col; // row within 32-row chunk
                const int tb = MT * 16 + g * 4;
                #pragma unroll
                for (int pass = 0; pass < 3; ++pass) {   // 0=Q(T) 1=K 2=V
                    f32x4 acc[4];
                    #pragma unroll
                    for (int n = 0; n < 4; ++n) acc[n] = (f32x4){0.f, 0.f, 0.f, 0.f};
                    #pragma unroll
                    for (int half = 0; half < 2; ++half) {
                        bf16x8 xf[6];
                        #pragma unroll
                        for (int k6 = 0; k6 < 6; ++k6)
                            xf[k6] = *reinterpret_cast<const bf16x8*>(
                                &SM[HOFF_XS + lr * HLDXS + (half * 6 + k6) * 32 + g * 8]);
                        #pragma unroll
                        for (int k6 = 0; k6 < 6; ++k6) {
                            const int kk = half * 6 + k6;
                            #pragma unroll
                            for (int n = 0; n < 4; ++n) {
                                const bf16x8 bb = *reinterpret_cast<const bf16x8*>(
                                    Wf + ((size_t)((pass * 4 + n) * 12 + kk) * 64 + lane) * 8);
                                // pass 0: D = W^T x^T = Q^T (A=W-frag, B=x-frag)
                                // pass 1/2: D = x W     (A=x-frag, B=W-frag)
                                acc[n] = (pass == 0) ? mfma16(bb, xf[k6], acc[n])
                                                     : mfma16(xf[k6], bb, acc[n]);
                            }
                        }
                    }
                    if (pass == 0) {
                        #pragma unroll
                        for (int n = 0; n < 4; ++n) {
                            Qlo[mt][n] = pack2(acc[n][0], acc[n][1]);
                            Qhi[mt][n] = pack2(acc[n][2], acc[n][3]);
                        }
                    } else if (pass == 1) {
                        #pragma unroll
                        for (int n = 0; n < 4; ++n)
                            #pragma unroll
                            for (int r = 0; r < 4; ++r)
                                SM[HOFF_K + (tb + r) * HLDK + n * 16 + col] = f2bf(acc[n][r]);
                    } else {
                        #pragma unroll
                        for (int n = 0; n < 4; ++n) {
                            Vlo[mt][n] = pack2(acc[n][0], acc[n][1]);
                            Vhi[mt][n] = pack2(acc[n][2], acc[n][3]);
                        }
                    }
                }
            }
        }
        __syncthreads();
    }

    // ---- deferred VT writes (XS region dead now) ----
    #pragma unroll
    for (int mt = 0; mt < 2; ++mt) {
        const int MT = mt ? (15 - w) : w;
        #pragma unroll
        for (int n = 0; n < 4; ++n) {
            u32x2 v; v[0] = Vlo[mt][n]; v[1] = Vhi[mt][n];
            *reinterpret_cast<u32x2*>(&SM[HOFF_VT + (n * 16 + col) * HLDVT + MT * 16 + g * 4]) = v;
        }
    }
    __syncthreads();

    // ---------------- phase 3: attention (swapped QK^T, shuffle PV) ----------
    const int hi_half = (lane >> 5) & 1;
    const int srcA = ((lane >> 4) & 1) * 32 + col;
    const int srcB = srcA + 16;

    #pragma unroll
    for (int mt = 0; mt < 2; ++mt) {
        const int MT = mt ? (15 - w) : w;

        // Q B-frags from QT register frags via shuffles (same pattern as P)
        bf16x8 qb[2];
        #pragma unroll
        for (int kk = 0; kk < 2; ++kk) {
            const unsigned qa0 = __shfl(Qlo[mt][2 * kk],     srcA, 64);
            const unsigned qa1 = __shfl(Qlo[mt][2 * kk + 1], srcA, 64);
            const unsigned qb0 = __shfl(Qhi[mt][2 * kk],     srcA, 64);
            const unsigned qb1 = __shfl(Qhi[mt][2 * kk + 1], srcA, 64);
            const unsigned qc0 = __shfl(Qlo[mt][2 * kk],     srcB, 64);
            const unsigned qc1 = __shfl(Qlo[mt][2 * kk + 1], srcB, 64);
            const unsigned qd0 = __shfl(Qhi[mt][2 * kk],     srcB, 64);
            const unsigned qd1 = __shfl(Qhi[mt][2 * kk + 1], srcB, 64);
            u32x4 wv;
            wv[0] = hi_half ? qa1 : qa0;
            wv[1] = hi_half ? qb1 : qb0;
            wv[2] = hi_half ? qc1 : qc0;
            wv[3] = hi_half ? qd1 : qd0;
            qb[kk] = __builtin_bit_cast(bf16x8, wv);
        }

        // scores S^T: lane holds S[s=nt*16+4g+r][t=MT*16+col]
        f32x4 sc[16];
        #pragma unroll
        for (int nt = 0; nt < 16; ++nt) {
            if (nt <= MT) {
                f32x4 a = {0.f, 0.f, 0.f, 0.f};
                const bf16x8 ka0 = *reinterpret_cast<const bf16x8*>(
                    &SM[HOFF_K + (nt * 16 + col) * HLDK + g * 8]);
                const bf16x8 ka1 = *reinterpret_cast<const bf16x8*>(
                    &SM[HOFF_K + (nt * 16 + col) * HLDK + 32 + g * 8]);
                a = mfma16(ka0, qb[0], a);
                a = mfma16(ka1, qb[1], a);
                sc[nt] = a;
            }
        }

        // softmax over s for row t=col; reduce across g with 2 shuffles
        float m = -INFINITY;
        #pragma unroll
        for (int nt = 0; nt < 16; ++nt) {
            if (nt <= MT) {
                #pragma unroll
                for (int r = 0; r < 4; ++r) {
                    float v = sc[nt][r] * 0.125f;
                    if (nt == MT && (4 * g + r) > col) v = -INFINITY;   // causal
                    sc[nt][r] = v;
                    m = fmaxf(m, v);
                }
            }
        }
        m = fmaxf(m, __shfl_xor(m, 16));
        m = fmaxf(m, __shfl_xor(m, 32));
        float s = 0.f;
        #pragma unroll
        for (int nt = 0; nt < 16; ++nt) {
            if (nt <= MT) {
                #pragma unroll
                for (int r = 0; r < 4; ++r) {
                    const float p = __expf(sc[nt][r] - m);
                    sc[nt][r] = p;
                    s += p;
                }
            }
        }
        s += __shfl_xor(s, 16);
        s += __shfl_xor(s, 32);
        const float inv = 1.0f / s;

        // normalized P -> bf16 pairs (per nt: r0|r1, r2|r3)
        unsigned P4lo[16], P4hi[16];
        #pragma unroll
        for (int nt = 0; nt < 16; ++nt) {
            if (nt <= MT) {
                P4lo[nt] = pack2(sc[nt][0] * inv, sc[nt][1] * inv);
                P4hi[nt] = pack2(sc[nt][2] * inv, sc[nt][3] * inv);
            } else { P4lo[nt] = 0u; P4hi[nt] = 0u; }
        }

        // PV: build P A-frags via shuffles (no LDS), accumulate O
        f32x4 oacc[4];
        #pragma unroll
        for (int n = 0; n < 4; ++n) oacc[n] = (f32x4){0.f, 0.f, 0.f, 0.f};
        #pragma unroll
        for (int cpv = 0; cpv < 8; ++cpv) {
            if (cpv <= (MT >> 1)) {
                const unsigned a0 = __shfl(P4lo[2 * cpv],     srcA, 64);
                const unsigned a1 = __shfl(P4lo[2 * cpv + 1], srcA, 64);
                const unsigned b0 = __shfl(P4hi[2 * cpv],     srcA, 64);
                const unsigned b1 = __shfl(P4hi[2 * cpv + 1], srcA, 64);
                const unsigned c0 = __shfl(P4lo[2 * cpv],     srcB, 64);
                const unsigned c1 = __shfl(P4lo[2 * cpv + 1], srcB, 64);
                const unsigned d0 = __shfl(P4hi[2 * cpv],     srcB, 64);
                const unsigned d1 = __shfl(P4hi[2 * cpv + 1], srcB, 64);
                u32x4 wv;
                wv[0] = hi_half ? a1 : a0;
                wv[1] = hi_half ? b1 : b0;
                wv[2] = hi_half ? c1 : c0;
                wv[3] = hi_half ? d1 : d0;
                const bf16x8 pa = __builtin_bit_cast(bf16x8, wv);
                #pragma unroll
                for (int n = 0; n < 4; ++n) {
                    const bf16x8 vb = *reinterpret_cast<const bf16x8*>(
                        &SM[HOFF_VT + (n * 16 + col) * HLDVT + cpv * 32 + g * 8]);
                    oacc[n] = mfma16(pa, vb, oacc[n]);
                }
            }
        }

        // store O (P already normalized)
        #pragma unroll
        for (int n = 0; n < 4; ++n)
            #pragma unroll
            for (int r = 0; r < 4; ++r)
                out[((size_t)b * NT + MT * 16 + 4 * g + r) * NH + n * 16 + col] = oacc[n][r];
    }
}

// ============ launcher =========================================================
extern "C" void kernel_launch(void* const* d_in, const int* in_sizes, int n_in,
                              void* d_out, int out_size, void* d_ws, size_t ws_size,
                              hipStream_t stream) {
    (void)in_sizes; (void)n_in; (void)out_size; (void)ws_size;
    const float* x  = (const float*)d_in[0];
    const float* wq = (const float*)d_in[1];
    const float* wk = (const float*)d_in[2];
    const float* wv = (const float*)d_in[3];
    float* o = (float*)d_out;

    unsigned short* Wf = (unsigned short*)d_ws;   // 147,456 B
    prep_w <<<dim3(288), dim3(256), 0, stream>>>(wq, wk, wv, Wf);
    head_v5<<<dim3(NB),  dim3(512), 0, stream>>>(x, Wf, o);
}

// Round 9
// 421.752 us; speedup vs baseline: 1.2592x; 1.2592x over previous
//
#include <hip/hip_runtime.h>
#include <hip/hip_bf16.h>
#include <math.h>

#define NB 512
#define NT 256
#define NC 384
#define NH 64

typedef __bf16 bf16x8 __attribute__((ext_vector_type(8)));
typedef unsigned short u16x8 __attribute__((ext_vector_type(8)));
typedef unsigned short u16x4 __attribute__((ext_vector_type(4)));
typedef unsigned int   u32x2 __attribute__((ext_vector_type(2)));
typedef unsigned int   u32x4 __attribute__((ext_vector_type(4)));
typedef float f32x4 __attribute__((ext_vector_type(4)));

__device__ __forceinline__ unsigned short f2bf(float f) {
    union { float f; unsigned u; } v; v.f = f;
    unsigned r = v.u + 0x7FFFu + ((v.u >> 16) & 1u);   // round-to-nearest-even
    return (unsigned short)(r >> 16);
}

__device__ __forceinline__ unsigned pack2(float a, float b) {
    return (unsigned)f2bf(a) | ((unsigned)f2bf(b) << 16);
}

__device__ __forceinline__ f32x4 mfma16(bf16x8 a, bf16x8 b, f32x4 c) {
    return __builtin_amdgcn_mfma_f32_16x16x32_bf16(a, b, c, 0, 0, 0);
}

// ============ kernel 1: W -> Wf (bf16, MFMA fragment packed) ===================
// Wf element e = ((n*12+kk)*64 + l)*8 + j  holds  W_m[c=kk*32+8*(l>>4)+j][h=(n&3)*16+(l&15)]
// Same lane map serves as A-frag (row=l&15, k=8g+j) and B-frag. (verified r4-r8)
__global__ void prep_w(const float* __restrict__ Wq, const float* __restrict__ Wk,
                       const float* __restrict__ Wv, unsigned short* __restrict__ Wf) {
    const int e = blockIdx.x * 256 + threadIdx.x;   // 0..73727
    const int j  = e & 7;
    const int l  = (e >> 3) & 63;
    const int fi = e >> 9;                          // 0..143
    const int kk = fi % 12;
    const int n  = fi / 12;
    const int g = l >> 4, col = l & 15;
    const int c = kk * 32 + g * 8 + j;
    const int h = (n & 3) * 16 + col;
    const float* W = (n < 4) ? Wq : (n < 8 ? Wk : Wv);
    Wf[e] = f2bf(W[c * 64 + h]);
}

// ============ kernel 2: fused head, 8 waves, 2 blocks/CU (LDS-limited) =========
// Wave w owns q-tiles {w, 15-w} (balanced causal). LDS (shorts):
//   K  [256][72]  @ 0       (immediate writes during chunk loop)
//   VT [64][264]  @ 18432   (deferred writes; region doubles as XS during staging)
//   XS [32][392]  @ 18432   (overlay; 32-row x chunks)
// Q never touches LDS: computed transposed (QT) and redistributed via shuffles.
// NOTE launch_bounds arg2: empirically hipcc budgets VGPRs for arg2*8 waves/CU
// here (r6:(512,2)->128 VGPR, r8:(512,4)->64 VGPR+spill). (512,2) => 128-VGPR
// budget; real occupancy is LDS-limited to 2 blocks/CU anyway.
#define HOFF_K   0
#define HLDK     72
#define HOFF_VT  18432
#define HLDVT    264
#define HOFF_XS  18432
#define HLDXS    392
#define HSMEM    35328          // 70,656 B -> 2 blocks/CU

__global__ __launch_bounds__(512, 2) void head_v5(
    const float* __restrict__ x, const unsigned short* __restrict__ Wf,
    float* __restrict__ out)
{
    __shared__ __align__(16) unsigned short SM[HSMEM];

    const int b    = blockIdx.x;
    const int tid  = threadIdx.x;
    const int w    = tid >> 6;       // wave 0..7
    const int lane = tid & 63;
    const int g    = lane >> 4;
    const int col  = lane & 15;

    unsigned Qlo[2][4], Qhi[2][4];   // QT D-frags, bf16-packed (per tile)
    unsigned Vlo[2][4], Vhi[2][4];   // V  D-frags, bf16-packed (per tile)

    // ---------------- phase 1+2: chunked staging + projection ----------------
    #pragma unroll 1
    for (int ch = 0; ch < 8; ++ch) {
        // stage 32 rows of x (coalesced float4 stream -> bf16 LDS)
        const float* xb = x + ((size_t)b * NT + ch * 32) * NC;
        #pragma unroll
        for (int k = 0; k < 3; ++k) {
            const int idx = k * 4096 + tid * 8;     // 512 thr x 8 f32
            const int row = idx / 384;              // 0..31
            const int cc  = idx - row * 384;
            const float4 f0 = *reinterpret_cast<const float4*>(xb + idx);
            const float4 f1 = *reinterpret_cast<const float4*>(xb + idx + 4);
            u16x8 u;
            u[0] = f2bf(f0.x); u[1] = f2bf(f0.y); u[2] = f2bf(f0.z); u[3] = f2bf(f0.w);
            u[4] = f2bf(f1.x); u[5] = f2bf(f1.y); u[6] = f2bf(f1.z); u[7] = f2bf(f1.w);
            *reinterpret_cast<u16x8*>(&SM[HOFF_XS + row * HLDXS + cc]) = u;
        }
        __syncthreads();

        #pragma unroll
        for (int mt = 0; mt < 2; ++mt) {
            const int MT = mt ? (15 - w) : w;
            if ((MT >> 1) == ch) {                  // wave-uniform ownership
                const int lr = (MT & 1) * 16 + col; // row within 32-row chunk
                const int tb = MT * 16 + g * 4;
                #pragma unroll
                for (int pass = 0; pass < 3; ++pass) {   // 0=Q(T) 1=K 2=V
                    f32x4 acc[4];
                    #pragma unroll
                    for (int n = 0; n < 4; ++n) acc[n] = (f32x4){0.f, 0.f, 0.f, 0.f};
                    #pragma unroll
                    for (int half = 0; half < 2; ++half) {
                        bf16x8 xf[6];
                        #pragma unroll
                        for (int k6 = 0; k6 < 6; ++k6)
                            xf[k6] = *reinterpret_cast<const bf16x8*>(
                                &SM[HOFF_XS + lr * HLDXS + (half * 6 + k6) * 32 + g * 8]);
                        #pragma unroll
                        for (int k6 = 0; k6 < 6; ++k6) {
                            const int kk = half * 6 + k6;
                            #pragma unroll
                            for (int n = 0; n < 4; ++n) {
                                const bf16x8 bb = *reinterpret_cast<const bf16x8*>(
                                    Wf + ((size_t)((pass * 4 + n) * 12 + kk) * 64 + lane) * 8);
                                // pass 0: D = W^T x^T = Q^T (A=W-frag, B=x-frag)
                                // pass 1/2: D = x W     (A=x-frag, B=W-frag)
                                acc[n] = (pass == 0) ? mfma16(bb, xf[k6], acc[n])
                                                     : mfma16(xf[k6], bb, acc[n]);
                            }
                        }
                    }
                    if (pass == 0) {
                        #pragma unroll
                        for (int n = 0; n < 4; ++n) {
                            Qlo[mt][n] = pack2(acc[n][0], acc[n][1]);
                            Qhi[mt][n] = pack2(acc[n][2], acc[n][3]);
                        }
                    } else if (pass == 1) {
                        #pragma unroll
                        for (int n = 0; n < 4; ++n)
                            #pragma unroll
                            for (int r = 0; r < 4; ++r)
                                SM[HOFF_K + (tb + r) * HLDK + n * 16 + col] = f2bf(acc[n][r]);
                    } else {
                        #pragma unroll
                        for (int n = 0; n < 4; ++n) {
                            Vlo[mt][n] = pack2(acc[n][0], acc[n][1]);
                            Vhi[mt][n] = pack2(acc[n][2], acc[n][3]);
                        }
                    }
                }
            }
        }
        __syncthreads();
    }

    // ---- deferred VT writes (XS region dead now) ----
    #pragma unroll
    for (int mt = 0; mt < 2; ++mt) {
        const int MT = mt ? (15 - w) : w;
        #pragma unroll
        for (int n = 0; n < 4; ++n) {
            u32x2 v; v[0] = Vlo[mt][n]; v[1] = Vhi[mt][n];
            *reinterpret_cast<u32x2*>(&SM[HOFF_VT + (n * 16 + col) * HLDVT + MT * 16 + g * 4]) = v;
        }
    }
    __syncthreads();

    // ---------------- phase 3: attention (swapped QK^T, shuffle PV) ----------
    const int hi_half = (lane >> 5) & 1;
    const int srcA = ((lane >> 4) & 1) * 32 + col;
    const int srcB = srcA + 16;

    #pragma unroll
    for (int mt = 0; mt < 2; ++mt) {
        const int MT = mt ? (15 - w) : w;

        // Q B-frags from QT register frags via shuffles (same pattern as P)
        bf16x8 qb[2];
        #pragma unroll
        for (int kk = 0; kk < 2; ++kk) {
            const unsigned qa0 = __shfl(Qlo[mt][2 * kk],     srcA, 64);
            const unsigned qa1 = __shfl(Qlo[mt][2 * kk + 1], srcA, 64);
            const unsigned qb0 = __shfl(Qhi[mt][2 * kk],     srcA, 64);
            const unsigned qb1 = __shfl(Qhi[mt][2 * kk + 1], srcA, 64);
            const unsigned qc0 = __shfl(Qlo[mt][2 * kk],     srcB, 64);
            const unsigned qc1 = __shfl(Qlo[mt][2 * kk + 1], srcB, 64);
            const unsigned qd0 = __shfl(Qhi[mt][2 * kk],     srcB, 64);
            const unsigned qd1 = __shfl(Qhi[mt][2 * kk + 1], srcB, 64);
            u32x4 wv;
            wv[0] = hi_half ? qa1 : qa0;
            wv[1] = hi_half ? qb1 : qb0;
            wv[2] = hi_half ? qc1 : qc0;
            wv[3] = hi_half ? qd1 : qd0;
            qb[kk] = __builtin_bit_cast(bf16x8, wv);
        }

        // scores S^T: lane holds S[s=nt*16+4g+r][t=MT*16+col]
        f32x4 sc[16];
        #pragma unroll
        for (int nt = 0; nt < 16; ++nt) {
            if (nt <= MT) {
                f32x4 a = {0.f, 0.f, 0.f, 0.f};
                const bf16x8 ka0 = *reinterpret_cast<const bf16x8*>(
                    &SM[HOFF_K + (nt * 16 + col) * HLDK + g * 8]);
                const bf16x8 ka1 = *reinterpret_cast<const bf16x8*>(
                    &SM[HOFF_K + (nt * 16 + col) * HLDK + 32 + g * 8]);
                a = mfma16(ka0, qb[0], a);
                a = mfma16(ka1, qb[1], a);
                sc[nt] = a;
            }
        }

        // softmax over s for row t=col; reduce across g with 2 shuffles
        float m = -INFINITY;
        #pragma unroll
        for (int nt = 0; nt < 16; ++nt) {
            if (nt <= MT) {
                #pragma unroll
                for (int r = 0; r < 4; ++r) {
                    float v = sc[nt][r] * 0.125f;
                    if (nt == MT && (4 * g + r) > col) v = -INFINITY;   // causal
                    sc[nt][r] = v;
                    m = fmaxf(m, v);
                }
            }
        }
        m = fmaxf(m, __shfl_xor(m, 16));
        m = fmaxf(m, __shfl_xor(m, 32));
        float s = 0.f;
        #pragma unroll
        for (int nt = 0; nt < 16; ++nt) {
            if (nt <= MT) {
                #pragma unroll
                for (int r = 0; r < 4; ++r) {
                    const float p = __expf(sc[nt][r] - m);
                    sc[nt][r] = p;
                    s += p;
                }
            }
        }
        s += __shfl_xor(s, 16);
        s += __shfl_xor(s, 32);
        const float inv = 1.0f / s;

        // normalized P -> bf16 pairs (per nt: r0|r1, r2|r3)
        unsigned P4lo[16], P4hi[16];
        #pragma unroll
        for (int nt = 0; nt < 16; ++nt) {
            if (nt <= MT) {
                P4lo[nt] = pack2(sc[nt][0] * inv, sc[nt][1] * inv);
                P4hi[nt] = pack2(sc[nt][2] * inv, sc[nt][3] * inv);
            } else { P4lo[nt] = 0u; P4hi[nt] = 0u; }
        }

        // PV: build P A-frags via shuffles (no LDS), accumulate O
        f32x4 oacc[4];
        #pragma unroll
        for (int n = 0; n < 4; ++n) oacc[n] = (f32x4){0.f, 0.f, 0.f, 0.f};
        #pragma unroll
        for (int cpv = 0; cpv < 8; ++cpv) {
            if (cpv <= (MT >> 1)) {
                const unsigned a0 = __shfl(P4lo[2 * cpv],     srcA, 64);
                const unsigned a1 = __shfl(P4lo[2 * cpv + 1], srcA, 64);
                const unsigned b0 = __shfl(P4hi[2 * cpv],     srcA, 64);
                const unsigned b1 = __shfl(P4hi[2 * cpv + 1], srcA, 64);
                const unsigned c0 = __shfl(P4lo[2 * cpv],     srcB, 64);
                const unsigned c1 = __shfl(P4lo[2 * cpv + 1], srcB, 64);
                const unsigned d0 = __shfl(P4hi[2 * cpv],     srcB, 64);
                const unsigned d1 = __shfl(P4hi[2 * cpv + 1], srcB, 64);
                u32x4 wv;
                wv[0] = hi_half ? a1 : a0;
                wv[1] = hi_half ? b1 : b0;
                wv[2] = hi_half ? c1 : c0;
                wv[3] = hi_half ? d1 : d0;
                const bf16x8 pa = __builtin_bit_cast(bf16x8, wv);
                #pragma unroll
                for (int n = 0; n < 4; ++n) {
                    const bf16x8 vb = *reinterpret_cast<const bf16x8*>(
                        &SM[HOFF_VT + (n * 16 + col) * HLDVT + cpv * 32 + g * 8]);
                    oacc[n] = mfma16(pa, vb, oacc[n]);
                }
            }
        }

        // store O (P already normalized)
        #pragma unroll
        for (int n = 0; n < 4; ++n)
            #pragma unroll
            for (int r = 0; r < 4; ++r)
                out[((size_t)b * NT + MT * 16 + 4 * g + r) * NH + n * 16 + col] = oacc[n][r];
    }
}

// ============ launcher =========================================================
extern "C" void kernel_launch(void* const* d_in, const int* in_sizes, int n_in,
                              void* d_out, int out_size, void* d_ws, size_t ws_size,
                              hipStream_t stream) {
    (void)in_sizes; (void)n_in; (void)out_size; (void)ws_size;
    const float* x  = (const float*)d_in[0];
    const float* wq = (const float*)d_in[1];
    const float* wk = (const float*)d_in[2];
    const float* wv = (const float*)d_in[3];
    float* o = (float*)d_out;

    unsigned short* Wf = (unsigned short*)d_ws;   // 147,456 B
    prep_w <<<dim3(288), dim3(256), 0, stream>>>(wq, wk, wv, Wf);
    head_v5<<<dim3(NB),  dim3(512), 0, stream>>>(x, Wf, o);
}

// Round 10
// 69.887 us; speedup vs baseline: 7.5987x; 6.0347x over previous
//
#include <hip/hip_runtime.h>
#include <hip/hip_bf16.h>
#include <math.h>

#define NB 512
#define NT 256
#define NC 384
#define NH 64

typedef __bf16 bf16x8 __attribute__((ext_vector_type(8)));
typedef unsigned short u16x8 __attribute__((ext_vector_type(8)));
typedef unsigned int   u32x4 __attribute__((ext_vector_type(4)));
typedef float f32x4 __attribute__((ext_vector_type(4)));

__device__ __forceinline__ unsigned short f2bf(float f) {
    union { float f; unsigned u; } v; v.f = f;
    unsigned r = v.u + 0x7FFFu + ((v.u >> 16) & 1u);   // round-to-nearest-even
    return (unsigned short)(r >> 16);
}

__device__ __forceinline__ unsigned pack2(float a, float b) {
    return (unsigned)f2bf(a) | ((unsigned)f2bf(b) << 16);
}

__device__ __forceinline__ f32x4 mfma16(bf16x8 a, bf16x8 b, f32x4 c) {
    return __builtin_amdgcn_mfma_f32_16x16x32_bf16(a, b, c, 0, 0, 0);
}

// ============ kernel 1: W -> Wf (bf16, MFMA fragment packed) ===================
// Wf element e = ((n*12+kk)*64 + l)*8 + j holds W_m[c=kk*32+8*(l>>4)+j][h=(n&3)*16+(l&15)]
// (verified r4-r9)
__global__ void prep_w(const float* __restrict__ Wq, const float* __restrict__ Wk,
                       const float* __restrict__ Wv, unsigned short* __restrict__ Wf) {
    const int e = blockIdx.x * 256 + threadIdx.x;   // 0..73727
    const int j  = e & 7;
    const int l  = (e >> 3) & 63;
    const int fi = e >> 9;                          // 0..143
    const int kk = fi % 12;
    const int n  = fi / 12;
    const int g = l >> 4, col = l & 15;
    const int c = kk * 32 + g * 8 + j;
    const int h = (n & 3) * 16 + col;
    const float* W = (n < 4) ? Wq : (n < 8 ? Wk : Wv);
    Wf[e] = f2bf(W[c * 64 + h]);
}

// ============ kernel 2: fused head, 16 waves, specialized projection ===========
// LDS (shorts):  Q [256][72] @0 | K [256][72] @18432 | VT [64][264] @36864
//                XS [64][392] @53760   (x staging, 4 chunks of 64 rows)
// Phase 2: wave j<12 owns (pass=j>>2, n=j&3); 12 Wf frags live in regs; computes
// its 16-col slice for all staged row-tiles (Wf L2 traffic 16x lower than v4).
// Phase 3: wave w owns q-tile T(w), permuted so each SIMD gets 34 score-tiles.
#define FOFF_Q   0
#define FLDQK    72
#define FOFF_K   18432
#define FOFF_VT  36864
#define FLDVT    264
#define FOFF_XS  53760
#define FLDXS    392
#define FSMEM    78848          // shorts = 157,696 B -> 1 block/CU, 16 waves

__global__ __launch_bounds__(1024, 1) void head_v6(
    const float* __restrict__ x, const unsigned short* __restrict__ Wf,
    float* __restrict__ out)
{
    __shared__ __align__(16) unsigned short SM[FSMEM];

    const int b    = blockIdx.x;
    const int tid  = threadIdx.x;
    const int w    = tid >> 6;       // wave 0..15
    const int lane = tid & 63;
    const int g    = lane >> 4;
    const int col  = lane & 15;

    // balanced q-tile permutation: each SIMD (w&3) totals 34 score-tiles
    const int wq2 = w >> 2;
    const int T = (wq2 == 0) ? w : (wq2 == 1) ? (19 - w) : (wq2 == 2) ? (15 - w) : (w - 4);

    // ---- phase-2 job: wave j<12 owns (pass, n); preload its 12 Wf frags ----
    const int pass = w >> 2;         // 0=Q 1=K 2=V (w<12)
    const int n    = w & 3;
    bf16x8 Bw[12];
    if (w < 12) {
        #pragma unroll
        for (int kk = 0; kk < 12; ++kk)
            Bw[kk] = *reinterpret_cast<const bf16x8*>(
                Wf + ((size_t)((pass * 4 + n) * 12 + kk) * 64 + lane) * 8);
    }

    // ---------------- phase 1+2: chunked staging + specialized projection ----
    #pragma unroll 1
    for (int ch = 0; ch < 4; ++ch) {
        // stage 64 rows of x (coalesced float4 stream -> bf16 LDS)
        const float* xb = x + ((size_t)b * NT + ch * 64) * NC;
        #pragma unroll
        for (int k = 0; k < 3; ++k) {
            const int idx = k * 8192 + tid * 8;     // 1024 thr x 8 f32
            const int row = idx / 384;              // 0..63
            const int cc  = idx - row * 384;
            const float4 f0 = *reinterpret_cast<const float4*>(xb + idx);
            const float4 f1 = *reinterpret_cast<const float4*>(xb + idx + 4);
            u16x8 u;
            u[0] = f2bf(f0.x); u[1] = f2bf(f0.y); u[2] = f2bf(f0.z); u[3] = f2bf(f0.w);
            u[4] = f2bf(f1.x); u[5] = f2bf(f1.y); u[6] = f2bf(f1.z); u[7] = f2bf(f1.w);
            *reinterpret_cast<u16x8*>(&SM[FOFF_XS + row * FLDXS + cc]) = u;
        }
        __syncthreads();

        if (w < 12) {
            #pragma unroll
            for (int rt = 0; rt < 4; ++rt) {        // row-tiles in this chunk
                const int tile = ch * 4 + rt;
                f32x4 acc = (f32x4){0.f, 0.f, 0.f, 0.f};
                #pragma unroll
                for (int kk = 0; kk < 12; ++kk) {
                    const bf16x8 xf = *reinterpret_cast<const bf16x8*>(
                        &SM[FOFF_XS + (rt * 16 + col) * FLDXS + kk * 32 + g * 8]);
                    acc = mfma16(xf, Bw[kk], acc);
                }
                const int tb = tile * 16 + g * 4;
                if (pass < 2) {
                    const int base = (pass == 0) ? FOFF_Q : FOFF_K;
                    #pragma unroll
                    for (int r = 0; r < 4; ++r)
                        SM[base + (tb + r) * FLDQK + n * 16 + col] = f2bf(acc[r]);
                } else {
                    #pragma unroll
                    for (int r = 0; r < 4; ++r)
                        SM[FOFF_VT + (n * 16 + col) * FLDVT + tb + r] = f2bf(acc[r]);
                }
            }
        }
        __syncthreads();
    }

    // ---------------- phase 3: attention (swapped QK^T, shuffle PV) ----------
    const int hi_half = (lane >> 5) & 1;
    const int srcA = ((lane >> 4) & 1) * 32 + col;
    const int srcB = srcA + 16;

    // Q B-frags from LDS rows (v3-proven pattern)
    bf16x8 qb[2];
    #pragma unroll
    for (int kk = 0; kk < 2; ++kk)
        qb[kk] = *reinterpret_cast<const bf16x8*>(
            &SM[FOFF_Q + (T * 16 + col) * FLDQK + kk * 32 + g * 8]);

    // scores S^T: lane holds S[s=nt*16+4g+r][t=T*16+col]
    f32x4 sc[16];
    #pragma unroll
    for (int nt = 0; nt < 16; ++nt) {
        if (nt <= T) {
            f32x4 a = {0.f, 0.f, 0.f, 0.f};
            const bf16x8 ka0 = *reinterpret_cast<const bf16x8*>(
                &SM[FOFF_K + (nt * 16 + col) * FLDQK + g * 8]);
            const bf16x8 ka1 = *reinterpret_cast<const bf16x8*>(
                &SM[FOFF_K + (nt * 16 + col) * FLDQK + 32 + g * 8]);
            a = mfma16(ka0, qb[0], a);
            a = mfma16(ka1, qb[1], a);
            sc[nt] = a;
        }
    }

    // softmax over s for row t=col; reduce across g with 2 shuffles
    float m = -INFINITY;
    #pragma unroll
    for (int nt = 0; nt < 16; ++nt) {
        if (nt <= T) {
            #pragma unroll
            for (int r = 0; r < 4; ++r) {
                float v = sc[nt][r] * 0.125f;
                if (nt == T && (4 * g + r) > col) v = -INFINITY;   // causal
                sc[nt][r] = v;
                m = fmaxf(m, v);
            }
        }
    }
    m = fmaxf(m, __shfl_xor(m, 16));
    m = fmaxf(m, __shfl_xor(m, 32));
    float s = 0.f;
    #pragma unroll
    for (int nt = 0; nt < 16; ++nt) {
        if (nt <= T) {
            #pragma unroll
            for (int r = 0; r < 4; ++r) {
                const float p = __expf(sc[nt][r] - m);
                sc[nt][r] = p;
                s += p;
            }
        }
    }
    s += __shfl_xor(s, 16);
    s += __shfl_xor(s, 32);
    const float inv = 1.0f / s;

    // normalized P -> bf16 pairs (per nt: r0|r1, r2|r3)
    unsigned P4lo[16], P4hi[16];
    #pragma unroll
    for (int nt = 0; nt < 16; ++nt) {
        if (nt <= T) {
            P4lo[nt] = pack2(sc[nt][0] * inv, sc[nt][1] * inv);
            P4hi[nt] = pack2(sc[nt][2] * inv, sc[nt][3] * inv);
        } else { P4lo[nt] = 0u; P4hi[nt] = 0u; }
    }

    // PV: build P A-frags via shuffles (no LDS), accumulate O
    f32x4 oacc[4];
    #pragma unroll
    for (int nn = 0; nn < 4; ++nn) oacc[nn] = (f32x4){0.f, 0.f, 0.f, 0.f};
    #pragma unroll
    for (int cpv = 0; cpv < 8; ++cpv) {
        if (cpv <= (T >> 1)) {
            const unsigned a0 = __shfl(P4lo[2 * cpv],     srcA, 64);
            const unsigned a1 = __shfl(P4lo[2 * cpv + 1], srcA, 64);
            const unsigned b0 = __shfl(P4hi[2 * cpv],     srcA, 64);
            const unsigned b1 = __shfl(P4hi[2 * cpv + 1], srcA, 64);
            const unsigned c0 = __shfl(P4lo[2 * cpv],     srcB, 64);
            const unsigned c1 = __shfl(P4lo[2 * cpv + 1], srcB, 64);
            const unsigned d0 = __shfl(P4hi[2 * cpv],     srcB, 64);
            const unsigned d1 = __shfl(P4hi[2 * cpv + 1], srcB, 64);
            u32x4 wv;
            wv[0] = hi_half ? a1 : a0;
            wv[1] = hi_half ? b1 : b0;
            wv[2] = hi_half ? c1 : c0;
            wv[3] = hi_half ? d1 : d0;
            const bf16x8 pa = __builtin_bit_cast(bf16x8, wv);
            #pragma unroll
            for (int nn = 0; nn < 4; ++nn) {
                const bf16x8 vb = *reinterpret_cast<const bf16x8*>(
                    &SM[FOFF_VT + (nn * 16 + col) * FLDVT + cpv * 32 + g * 8]);
                oacc[nn] = mfma16(pa, vb, oacc[nn]);
            }
        }
    }

    // store O (P already normalized)
    #pragma unroll
    for (int nn = 0; nn < 4; ++nn)
        #pragma unroll
        for (int r = 0; r < 4; ++r)
            out[((size_t)b * NT + T * 16 + 4 * g + r) * NH + nn * 16 + col] = oacc[nn][r];
}

// ============ launcher =========================================================
extern "C" void kernel_launch(void* const* d_in, const int* in_sizes, int n_in,
                              void* d_out, int out_size, void* d_ws, size_t ws_size,
                              hipStream_t stream) {
    (void)in_sizes; (void)n_in; (void)out_size; (void)ws_size;
    const float* x  = (const float*)d_in[0];
    const float* wq = (const float*)d_in[1];
    const float* wk = (const float*)d_in[2];
    const float* wv = (const float*)d_in[3];
    float* o = (float*)d_out;

    unsigned short* Wf = (unsigned short*)d_ws;   // 147,456 B
    prep_w <<<dim3(288), dim3(256),  0, stream>>>(wq, wk, wv, Wf);
    head_v6<<<dim3(NB),  dim3(1024), 0, stream>>>(x, Wf, o);
}

// Round 11
// 58.173 us; speedup vs baseline: 9.1289x; 1.2014x over previous
//
#include <hip/hip_runtime.h>
#include <hip/hip_bf16.h>
#include <math.h>

#define NB 512
#define NT 256
#define NC 384
#define NH 64

typedef __bf16 bf16x8 __attribute__((ext_vector_type(8)));
typedef unsigned short u16x8 __attribute__((ext_vector_type(8)));
typedef unsigned short u16x4 __attribute__((ext_vector_type(4)));
typedef unsigned int   u32x4 __attribute__((ext_vector_type(4)));
typedef float f32x4 __attribute__((ext_vector_type(4)));

__device__ __forceinline__ unsigned short f2bf(float f) {
    union { float f; unsigned u; } v; v.f = f;
    unsigned r = v.u + 0x7FFFu + ((v.u >> 16) & 1u);   // round-to-nearest-even
    return (unsigned short)(r >> 16);
}

__device__ __forceinline__ unsigned pack2(float a, float b) {
    return (unsigned)f2bf(a) | ((unsigned)f2bf(b) << 16);
}

__device__ __forceinline__ f32x4 mfma16(bf16x8 a, bf16x8 b, f32x4 c) {
    return __builtin_amdgcn_mfma_f32_16x16x32_bf16(a, b, c, 0, 0, 0);
}

// ============ kernel 1: W -> Wf (bf16, MFMA fragment packed) ===================
// Wf element e = ((n*12+kk)*64 + l)*8 + j holds W_m[c=kk*32+8*(l>>4)+j][h=(n&3)*16+(l&15)]
// (verified r4-r10)
__global__ void prep_w(const float* __restrict__ Wq, const float* __restrict__ Wk,
                       const float* __restrict__ Wv, unsigned short* __restrict__ Wf) {
    const int e = blockIdx.x * 256 + threadIdx.x;   // 0..73727
    const int j  = e & 7;
    const int l  = (e >> 3) & 63;
    const int fi = e >> 9;                          // 0..143
    const int kk = fi % 12;
    const int n  = fi / 12;
    const int g = l >> 4, col = l & 15;
    const int c = kk * 32 + g * 8 + j;
    const int h = (n & 3) * 16 + col;
    const float* W = (n < 4) ? Wq : (n < 8 ? Wk : Wv);
    Wf[e] = f2bf(W[c * 64 + h]);
}

// ============ kernel 2: fused head, 16 waves, async double-buffered staging ====
// LDS (shorts):  Q [256][72] @0 | K [256][72] @18432 | VT [64][264] @36864
//                XS[2][32][392] @53760 (ping-pong x staging, 8 chunks of 32 rows)
// Phase 2: wave j<12 owns (pass=j>>2, n=j&3) with its 12 Wf frags in regs.
// T14 async-stage: chunk c+1's global loads issue BEFORE compute(c); LDS write
// lands after the post-compute barrier -> HBM latency/BW hides under MFMA.
// Phase 3: wave w owns q-tile T(w), permuted so each SIMD gets 34 score-tiles.
#define FOFF_Q   0
#define FLDQK    72
#define FOFF_K   18432
#define FOFF_VT  36864
#define FLDVT    264
#define FOFF_XS0 53760
#define FOFF_XS1 66304
#define FLDXS    392
#define FSMEM    78848          // shorts = 157,696 B -> 1 block/CU, 16 waves

__global__ __launch_bounds__(1024, 1) void head_v7(
    const float* __restrict__ x, const unsigned short* __restrict__ Wf,
    float* __restrict__ out)
{
    __shared__ __align__(16) unsigned short SM[FSMEM];

    const int b    = blockIdx.x;
    const int tid  = threadIdx.x;
    const int w    = tid >> 6;       // wave 0..15
    const int lane = tid & 63;
    const int g    = lane >> 4;
    const int col  = lane & 15;

    // balanced q-tile permutation: each SIMD (w&3) totals 34 score-tiles
    const int wq2 = w >> 2;
    const int T = (wq2 == 0) ? w : (wq2 == 1) ? (19 - w) : (wq2 == 2) ? (15 - w) : (w - 4);

    // ---- phase-2 job: wave j<12 owns (pass, n); preload its 12 Wf frags ----
    const int pass = w >> 2;         // 0=Q 1=K 2=V (w<12)
    const int n    = w & 3;
    bf16x8 Bw[12];
    if (w < 12) {
        #pragma unroll
        for (int kk = 0; kk < 12; ++kk)
            Bw[kk] = *reinterpret_cast<const bf16x8*>(
                Wf + ((size_t)((pass * 4 + n) * 12 + kk) * 64 + lane) * 8);
    }

    // per-thread staging geometry: 32 rows x 384 f32 = 12288 = 1024 thr x 3 float4
    const int srow[3] = { (tid * 4) / 384, (4096 + tid * 4) / 384, (8192 + tid * 4) / 384 };
    const int scol[3] = { (tid * 4) % 384, (4096 + tid * 4) % 384, (8192 + tid * 4) % 384 };

    // ---- prologue: stage chunk 0 ----
    {
        const float* xb = x + (size_t)b * NT * NC;
        float4 pre[3];
        #pragma unroll
        for (int k = 0; k < 3; ++k)
            pre[k] = *reinterpret_cast<const float4*>(xb + k * 4096 + tid * 4);
        #pragma unroll
        for (int k = 0; k < 3; ++k) {
            u16x4 u;
            u[0] = f2bf(pre[k].x); u[1] = f2bf(pre[k].y);
            u[2] = f2bf(pre[k].z); u[3] = f2bf(pre[k].w);
            *reinterpret_cast<u16x4*>(&SM[FOFF_XS0 + srow[k] * FLDXS + scol[k]]) = u;
        }
    }
    __syncthreads();

    // ---- main loop: 8 chunks of 32 rows, ping-pong ----
    #pragma unroll 1
    for (int ch = 0; ch < 8; ++ch) {
        // issue next chunk's global loads FIRST (latency hides under compute)
        float4 nxt[3];
        if (ch < 7) {
            const float* xb = x + ((size_t)b * NT + (ch + 1) * 32) * NC;
            #pragma unroll
            for (int k = 0; k < 3; ++k)
                nxt[k] = *reinterpret_cast<const float4*>(xb + k * 4096 + tid * 4);
        }

        // compute chunk ch from buf[ch&1]
        const int xsbase = (ch & 1) ? FOFF_XS1 : FOFF_XS0;
        if (w < 12) {
            #pragma unroll
            for (int rt = 0; rt < 2; ++rt) {        // two 16-row tiles per chunk
                const int tile = ch * 2 + rt;
                f32x4 acc = (f32x4){0.f, 0.f, 0.f, 0.f};
                #pragma unroll
                for (int kk = 0; kk < 12; ++kk) {
                    const bf16x8 xf = *reinterpret_cast<const bf16x8*>(
                        &SM[xsbase + (rt * 16 + col) * FLDXS + kk * 32 + g * 8]);
                    acc = mfma16(xf, Bw[kk], acc);
                }
                const int tb = tile * 16 + g * 4;
                if (pass < 2) {
                    const int base = (pass == 0) ? FOFF_Q : FOFF_K;
                    #pragma unroll
                    for (int r = 0; r < 4; ++r)
                        SM[base + (tb + r) * FLDQK + n * 16 + col] = f2bf(acc[r]);
                } else {
                    #pragma unroll
                    for (int r = 0; r < 4; ++r)
                        SM[FOFF_VT + (n * 16 + col) * FLDVT + tb + r] = f2bf(acc[r]);
                }
            }
        }
        __syncthreads();    // compute(ch) done; safe to overwrite buf[(ch+1)&1]

        if (ch < 7) {
            const int nb = ((ch + 1) & 1) ? FOFF_XS1 : FOFF_XS0;
            #pragma unroll
            for (int k = 0; k < 3; ++k) {
                u16x4 u;
                u[0] = f2bf(nxt[k].x); u[1] = f2bf(nxt[k].y);
                u[2] = f2bf(nxt[k].z); u[3] = f2bf(nxt[k].w);
                *reinterpret_cast<u16x4*>(&SM[nb + srow[k] * FLDXS + scol[k]]) = u;
            }
        }
        __syncthreads();    // buf[(ch+1)&1] visible for next compute
    }

    // ---------------- phase 3: attention (swapped QK^T, shuffle PV) ----------
    const int hi_half = (lane >> 5) & 1;
    const int srcA = ((lane >> 4) & 1) * 32 + col;
    const int srcB = srcA + 16;

    // Q B-frags from LDS rows (v3-proven pattern)
    bf16x8 qb[2];
    #pragma unroll
    for (int kk = 0; kk < 2; ++kk)
        qb[kk] = *reinterpret_cast<const bf16x8*>(
            &SM[FOFF_Q + (T * 16 + col) * FLDQK + kk * 32 + g * 8]);

    // scores S^T: lane holds S[s=nt*16+4g+r][t=T*16+col]
    f32x4 sc[16];
    #pragma unroll
    for (int nt = 0; nt < 16; ++nt) {
        if (nt <= T) {
            f32x4 a = {0.f, 0.f, 0.f, 0.f};
            const bf16x8 ka0 = *reinterpret_cast<const bf16x8*>(
                &SM[FOFF_K + (nt * 16 + col) * FLDQK + g * 8]);
            const bf16x8 ka1 = *reinterpret_cast<const bf16x8*>(
                &SM[FOFF_K + (nt * 16 + col) * FLDQK + 32 + g * 8]);
            a = mfma16(ka0, qb[0], a);
            a = mfma16(ka1, qb[1], a);
            sc[nt] = a;
        }
    }

    // softmax over s for row t=col; reduce across g with 2 shuffles
    float m = -INFINITY;
    #pragma unroll
    for (int nt = 0; nt < 16; ++nt) {
        if (nt <= T) {
            #pragma unroll
            for (int r = 0; r < 4; ++r) {
                float v = sc[nt][r] * 0.125f;
                if (nt == T && (4 * g + r) > col) v = -INFINITY;   // causal
                sc[nt][r] = v;
                m = fmaxf(m, v);
            }
        }
    }
    m = fmaxf(m, __shfl_xor(m, 16));
    m = fmaxf(m, __shfl_xor(m, 32));
    float s = 0.f;
    #pragma unroll
    for (int nt = 0; nt < 16; ++nt) {
        if (nt <= T) {
            #pragma unroll
            for (int r = 0; r < 4; ++r) {
                const float p = __expf(sc[nt][r] - m);
                sc[nt][r] = p;
                s += p;
            }
        }
    }
    s += __shfl_xor(s, 16);
    s += __shfl_xor(s, 32);
    const float inv = 1.0f / s;

    // normalized P -> bf16 pairs (per nt: r0|r1, r2|r3)
    unsigned P4lo[16], P4hi[16];
    #pragma unroll
    for (int nt = 0; nt < 16; ++nt) {
        if (nt <= T) {
            P4lo[nt] = pack2(sc[nt][0] * inv, sc[nt][1] * inv);
            P4hi[nt] = pack2(sc[nt][2] * inv, sc[nt][3] * inv);
        } else { P4lo[nt] = 0u; P4hi[nt] = 0u; }
    }

    // PV: build P A-frags via shuffles (no LDS), accumulate O
    f32x4 oacc[4];
    #pragma unroll
    for (int nn = 0; nn < 4; ++nn) oacc[nn] = (f32x4){0.f, 0.f, 0.f, 0.f};
    #pragma unroll
    for (int cpv = 0; cpv < 8; ++cpv) {
        if (cpv <= (T >> 1)) {
            const unsigned a0 = __shfl(P4lo[2 * cpv],     srcA, 64);
            const unsigned a1 = __shfl(P4lo[2 * cpv + 1], srcA, 64);
            const unsigned b0 = __shfl(P4hi[2 * cpv],     srcA, 64);
            const unsigned b1 = __shfl(P4hi[2 * cpv + 1], srcA, 64);
            const unsigned c0 = __shfl(P4lo[2 * cpv],     srcB, 64);
            const unsigned c1 = __shfl(P4lo[2 * cpv + 1], srcB, 64);
            const unsigned d0 = __shfl(P4hi[2 * cpv],     srcB, 64);
            const unsigned d1 = __shfl(P4hi[2 * cpv + 1], srcB, 64);
            u32x4 wv;
            wv[0] = hi_half ? a1 : a0;
            wv[1] = hi_half ? b1 : b0;
            wv[2] = hi_half ? c1 : c0;
            wv[3] = hi_half ? d1 : d0;
            const bf16x8 pa = __builtin_bit_cast(bf16x8, wv);
            #pragma unroll
            for (int nn = 0; nn < 4; ++nn) {
                const bf16x8 vb = *reinterpret_cast<const bf16x8*>(
                    &SM[FOFF_VT + (nn * 16 + col) * FLDVT + cpv * 32 + g * 8]);
                oacc[nn] = mfma16(pa, vb, oacc[nn]);
            }
        }
    }

    // store O (P already normalized)
    #pragma unroll
    for (int nn = 0; nn < 4; ++nn)
        #pragma unroll
        for (int r = 0; r < 4; ++r)
            out[((size_t)b * NT + T * 16 + 4 * g + r) * NH + nn * 16 + col] = oacc[nn][r];
}

// ============ launcher =========================================================
extern "C" void kernel_launch(void* const* d_in, const int* in_sizes, int n_in,
                              void* d_out, int out_size, void* d_ws, size_t ws_size,
                              hipStream_t stream) {
    (void)in_sizes; (void)n_in; (void)out_size; (void)ws_size;
    const float* x  = (const float*)d_in[0];
    const float* wq = (const float*)d_in[1];
    const float* wk = (const float*)d_in[2];
    const float* wv = (const float*)d_in[3];
    float* o = (float*)d_out;

    unsigned short* Wf = (unsigned short*)d_ws;   // 147,456 B
    prep_w <<<dim3(288), dim3(256),  0, stream>>>(wq, wk, wv, Wf);
    head_v7<<<dim3(NB),  dim3(1024), 0, stream>>>(x, Wf, o);
}